// Round 1
// baseline (61.725 us; speedup 1.0000x reference)
//
#include <hip/hip_runtime.h>

#define KH 16
#define KW 16
#define E  256   // KH*KW

// ---------------------------------------------------------------------------
// Prep: ws[0..255] = column sums of weight (sum over output features j of
// W[j,i]), ws[256] = sum of bias. Tiny kernel (256 KB read), one block.
// ---------------------------------------------------------------------------
__global__ void DummyConv_prep_kernel(const float* __restrict__ weight,
                                      const float* __restrict__ bias,
                                      float* __restrict__ ws) {
    const int i = threadIdx.x;  // 0..255
    float s = 0.f;
    // coalesced: consecutive threads read consecutive i within each row j
    for (int j = 0; j < E; ++j) s += weight[j * E + i];
    ws[i] = s;
    if (i == 0) {
        float b = 0.f;
        for (int j = 0; j < E; ++j) b += bias[j];
        ws[E] = b;
    }
}

// ---------------------------------------------------------------------------
// Main: each block = 16 rows x 256 cols tile of data = 16 patches.
// 256 threads: thread t -> column-group c4 = t&63 (float4), row-quad t>>6.
// 4 passes cover the 16 rows. Per-row wave read = 64 lanes x 16B = 1 KiB
// contiguous (perfectly coalesced).
// ---------------------------------------------------------------------------
__global__ __launch_bounds__(256) void DummyConv_main_kernel(
    const float* __restrict__ data,
    const float* __restrict__ ws,
    float* __restrict__ out) {
    constexpr int W  = 8192;  // data width
    constexpr int GW = 512;   // patch grid width

    __shared__ __align__(16) float wsum[E];
    __shared__ float bsum_s;
    __shared__ float partials[64];  // 16 patches x 4 row-quads

    const int t = threadIdx.x;
    wsum[t] = ws[t];
    if (t == 0) bsum_s = ws[E];
    __syncthreads();

    const int tileX = blockIdx.x & 31;   // 32 column tiles of 256 cols
    const int gy    = blockIdx.x >> 5;   // 512 patch-row groups
    const long rowBase = (long)gy * KH;
    const int  colBase = tileX * 256;

    const int c4    = t & 63;        // float4 column group in tile
    const int rquad = t >> 6;        // 0..3 (== wave id)
    const int pc    = c4 >> 2;       // patch column within tile, 0..15
    const int wcol  = (t & 3) * 4;   // col-within-patch of this float4

    float acc = 0.f;
#pragma unroll
    for (int p = 0; p < 4; ++p) {
        const int r = rquad + p * 4;  // row within tile == row within patch
        const float4 d = *reinterpret_cast<const float4*>(
            data + (rowBase + r) * (long)W + colBase + c4 * 4);
        const float4 w = *reinterpret_cast<const float4*>(&wsum[r * KW + wcol]);
        acc += d.x * w.x + d.y * w.y + d.z * w.z + d.w * w.w;
    }

    // reduce the 4 lanes sharing one patch-column strip (same wave, adjacent)
    acc += __shfl_xor(acc, 1);
    acc += __shfl_xor(acc, 2);
    if ((t & 3) == 0) partials[pc * 4 + rquad] = acc;
    __syncthreads();

    if (t < 16) {
        const float s = partials[t * 4 + 0] + partials[t * 4 + 1] +
                        partials[t * 4 + 2] + partials[t * 4 + 3] + bsum_s;
        out[(long)gy * GW + tileX * 16 + t] = s;
    }
}

extern "C" void kernel_launch(void* const* d_in, const int* in_sizes, int n_in,
                              void* d_out, int out_size, void* d_ws, size_t ws_size,
                              hipStream_t stream) {
    const float* data   = (const float*)d_in[0];
    const float* weight = (const float*)d_in[1];
    const float* bias   = (const float*)d_in[2];
    float* out = (float*)d_out;
    float* ws  = (float*)d_ws;  // needs (E+1) floats

    DummyConv_prep_kernel<<<1, 256, 0, stream>>>(weight, bias, ws);

    // 512 row groups x 32 column tiles = 16384 blocks
    DummyConv_main_kernel<<<512 * 32, 256, 0, stream>>>(data, ws, out);
}

// Round 3
// 57.203 us; speedup vs baseline: 1.0791x; 1.0791x over previous
//
#include <hip/hip_runtime.h>

#define KH 16
#define KW 16
#define E  256   // KH*KW

typedef float f32x4 __attribute__((ext_vector_type(4)));

// ---------------------------------------------------------------------------
// Prep: ws[0..255] = column sums of weight (over output features j),
// ws[256] = sum of bias. 1024 threads, vectorized + LDS reduce.
// ---------------------------------------------------------------------------
__global__ __launch_bounds__(1024) void DummyConv_prep_kernel(
    const float* __restrict__ weight,
    const float* __restrict__ bias,
    float* __restrict__ ws) {
    __shared__ __align__(16) f32x4 red[1024];   // 16 KB
    __shared__ float bred[4];

    const int t  = threadIdx.x;
    const int c4 = t & 63;
    const int j0 = t >> 6;   // 0..15

    f32x4 a = {0.f, 0.f, 0.f, 0.f};
    for (int j = j0; j < E; j += 16) {
        a += *reinterpret_cast<const f32x4*>(&weight[j * E + c4 * 4]);
    }
    red[t] = a;

    // bias sum: first 4 waves reduce 256 bias values
    if (t < E) {
        float b = bias[t];
        b += __shfl_xor(b, 1);  b += __shfl_xor(b, 2);  b += __shfl_xor(b, 4);
        b += __shfl_xor(b, 8);  b += __shfl_xor(b, 16); b += __shfl_xor(b, 32);
        if ((t & 63) == 0) bred[t >> 6] = b;
    }
    __syncthreads();

    if (t < 64) {
        f32x4 s = {0.f, 0.f, 0.f, 0.f};
#pragma unroll
        for (int k = 0; k < 16; ++k) s += red[k * 64 + t];
        *reinterpret_cast<f32x4*>(&ws[t * 4]) = s;
        if (t == 0) ws[E] = bred[0] + bred[1] + bred[2] + bred[3];
    }
}

// ---------------------------------------------------------------------------
// Main: each block = 64 rows x 256 cols of data = 4x16 patches = 64 outputs.
// 256 threads: c4 = t&63 (float4 col group), rquad = t>>6 (row mod 4).
// Weight fragments hoisted to 4 registers; data loads non-temporal.
// ---------------------------------------------------------------------------
__global__ __launch_bounds__(256) void DummyConv_main_kernel(
    const float* __restrict__ data,
    const float* __restrict__ ws,
    float* __restrict__ out) {
    constexpr int W  = 8192;  // data width
    constexpr int GW = 512;   // patch grid width

    __shared__ __align__(16) float wsum[E];
    __shared__ float bsum_s;
    __shared__ float partials[4][64];  // [patch-row][patch-col*4 + rquad]

    const int t = threadIdx.x;
    wsum[t] = ws[t];
    if (t == 0) bsum_s = ws[E];
    __syncthreads();

    const int tileX = blockIdx.x & 31;   // 32 column tiles of 256 cols
    const int gq    = blockIdx.x >> 5;   // 128 groups of 4 patch-rows
    const long rowBase = (long)gq * 64;
    const int  colBase = tileX * 256;

    const int c4    = t & 63;        // float4 column group in tile
    const int rquad = t >> 6;        // 0..3 (== wave id)
    const int pc    = c4 >> 2;       // patch column within tile, 0..15
    const int wcol  = (t & 3) * 4;   // col-within-patch of this float4

    // weight fragments: row-within-patch = rquad + p*4, shared by all patch-rows
    f32x4 wv[4];
#pragma unroll
    for (int p = 0; p < 4; ++p)
        wv[p] = *reinterpret_cast<const f32x4*>(&wsum[(rquad + p * 4) * KW + wcol]);

    float acc[4] = {0.f, 0.f, 0.f, 0.f};
#pragma unroll
    for (int pr = 0; pr < 4; ++pr) {
#pragma unroll
        for (int p = 0; p < 4; ++p) {
            const long r = rowBase + pr * 16 + rquad + p * 4;
            const f32x4 d = __builtin_nontemporal_load(
                reinterpret_cast<const f32x4*>(data + r * W + colBase + c4 * 4));
            acc[pr] += d.x * wv[p].x + d.y * wv[p].y + d.z * wv[p].z + d.w * wv[p].w;
        }
    }

#pragma unroll
    for (int pr = 0; pr < 4; ++pr) {
        float a = acc[pr];
        a += __shfl_xor(a, 1);
        a += __shfl_xor(a, 2);
        if ((t & 3) == 0) partials[pr][pc * 4 + rquad] = a;
    }
    __syncthreads();

    if (t < 64) {
        const int pr  = t >> 4;
        const int pcc = t & 15;
        const float s = partials[pr][pcc * 4 + 0] + partials[pr][pcc * 4 + 1] +
                        partials[pr][pcc * 4 + 2] + partials[pr][pcc * 4 + 3] + bsum_s;
        out[((long)gq * 4 + pr) * GW + tileX * 16 + pcc] = s;
    }
}

extern "C" void kernel_launch(void* const* d_in, const int* in_sizes, int n_in,
                              void* d_out, int out_size, void* d_ws, size_t ws_size,
                              hipStream_t stream) {
    const float* data   = (const float*)d_in[0];
    const float* weight = (const float*)d_in[1];
    const float* bias   = (const float*)d_in[2];
    float* out = (float*)d_out;
    float* ws  = (float*)d_ws;  // needs (E+1) floats

    DummyConv_prep_kernel<<<1, 1024, 0, stream>>>(weight, bias, ws);

    // 128 row groups x 32 column tiles = 4096 blocks, 64 outputs each
    DummyConv_main_kernel<<<4096, 256, 0, stream>>>(data, ws, out);
}